// Round 1
// 268.929 us; speedup vs baseline: 1.0930x; 1.0930x over previous
//
#include <hip/hip_runtime.h>
#include <hip/hip_bf16.h>
#include <cstdint>
#include <cstddef>

#define B_  8
#define N_  1024
#define D_  768
#define H_  12
#define DH_ 64
#define M_  (B_*N_)     // 8192 rows of X
#define D3_ (3*D_)      // 2304

typedef __bf16 bf16;
typedef __bf16 bf16x4 __attribute__((ext_vector_type(4)));
typedef __bf16 bf16x8 __attribute__((ext_vector_type(8)));
typedef float  floatx4 __attribute__((ext_vector_type(4)));

// async global->LDS, 16B/lane; LDS dest = wave-uniform base + lane*16 (m97/m104)
__device__ __forceinline__ void async16(const void* g, void* l) {
  __builtin_amdgcn_global_load_lds(
      (const __attribute__((address_space(1))) unsigned int*)g,
      (__attribute__((address_space(3))) unsigned int*)l, 16, 0, 0);
}

// ------------- detect dtype (bf16 vs fp32) + ingest small tensors ------------
__global__ __launch_bounds__(256) void detect_small_k(
    const unsigned int* __restrict__ xraw, const void* bq, const void* bp,
    const void* gm, int* __restrict__ flag, bf16* bqd, bf16* bpd, float* gmd) {
  __shared__ int sc;
  if (threadIdx.x == 0) sc = 0;
  __syncthreads();
  int cnt = 0;
  for (int j = 0; j < 8; j++) {
    unsigned int w = xraw[threadIdx.x * 8 + j];
    unsigned int e = (w >> 7) & 0xFF;
    cnt += (e >= 100 && e <= 140) ? 1 : 0;
  }
  atomicAdd(&sc, cnt);
  __syncthreads();
  int f = (sc > 1024) ? 1 : 0;   // bf16 if low-u16 exponents look normal
  if (threadIdx.x == 0) *flag = f;
  for (int i = threadIdx.x; i < D3_; i += 256)
    bqd[i] = f ? ((const bf16*)bq)[i] : (bf16)((const float*)bq)[i];
  for (int i = threadIdx.x; i < D_; i += 256)
    bpd[i] = f ? ((const bf16*)bp)[i] : (bf16)((const float*)bp)[i];
  if (threadIdx.x < B_)
    gmd[threadIdx.x] = f ? (float)((const bf16*)gm)[threadIdx.x]
                         : ((const float*)gm)[threadIdx.x];
}

// ---------- bulk ingest, x + dist in one launch (vectorized x4) --------------
__device__ __forceinline__ void ingest_span(const void* src, bf16* dst, int f,
                                            long n4, long i0, long stride) {
  if (f) {
    const ushort2* s = (const ushort2*)src;
    ushort2* d = (ushort2*)dst;
    for (long i = i0; i < n4 * 2; i += stride) d[i] = s[i];
  } else {
    const float4* s = (const float4*)src;
    for (long i = i0; i < n4; i += stride) {
      float4 v = s[i];
      bf16x4 o = { (bf16)v.x, (bf16)v.y, (bf16)v.z, (bf16)v.w };
      *(bf16x4*)(dst + i * 4) = o;
    }
  }
}
#define XBLOCKS 1024
#define DBLOCKS 256
__global__ __launch_bounds__(256) void ingest2_k(const void* __restrict__ x,
                                                 bf16* __restrict__ xb,
                                                 const void* __restrict__ dist,
                                                 bf16* __restrict__ distb,
                                                 const int* __restrict__ flag) {
  int f = *flag;
  if (blockIdx.x < XBLOCKS) {
    long i0 = (long)blockIdx.x * 256 + threadIdx.x;
    ingest_span(x, xb, f, (long)M_ * D_ / 4, i0, (long)XBLOCKS * 256);
  } else {
    long i0 = (long)(blockIdx.x - XBLOCKS) * 256 + threadIdx.x;
    ingest_span(dist, distb, f, (long)N_ * N_ / 4, i0, (long)DBLOCKS * 256);
  }
}

// ------- tiled ingest+transpose of both weights: src[R][C] -> dst[C][R] ------
__global__ __launch_bounds__(256) void ingest_wt_k(const void* srcA, bf16* dstA,
                                                   const void* srcB, bf16* dstB,
                                                   const int* __restrict__ flag,
                                                   int tilesA, int tcA) {
  __shared__ bf16 t[64][72];
  int f = *flag;
  int bid = blockIdx.x;
  const void* src; bf16* dst; int C;
  int tc;
  if (bid < tilesA) { src = srcA; dst = dstA; C = D3_; tc = tcA; }
  else { bid -= tilesA; src = srcB; dst = dstB; C = D_; tc = D_ / 64; }
  int c0 = (bid % tc) * 64, r0 = (bid / tc) * 64;
  int i = threadIdx.x >> 2, j0 = (threadIdx.x & 3) * 16;
  if (f) {
    const bf16* s = (const bf16*)src + (size_t)(r0 + i) * C + c0 + j0;
#pragma unroll
    for (int jj = 0; jj < 16; jj += 8) *(bf16x8*)&t[i][j0 + jj] = *(const bf16x8*)(s + jj);
  } else {
    const float4* s = (const float4*)((const float*)src + (size_t)(r0 + i) * C + c0 + j0);
#pragma unroll
    for (int jj = 0; jj < 4; jj++) {
      float4 v = s[jj];
      bf16x4 o = { (bf16)v.x, (bf16)v.y, (bf16)v.z, (bf16)v.w };
      *(bf16x4*)&t[i][j0 + jj * 4] = o;
    }
  }
  __syncthreads();
  bf16* d = dst + (size_t)(c0 + i) * D_ + r0 + j0;   // R = D_ always
#pragma unroll
  for (int jj = 0; jj < 16; jj++) d[jj] = t[j0 + jj][i];
}

// ---------------- GEMM: C = A[M][K] * Bt[N][K]^T + bias ----------------------
// R7 double-buffered K-loop + XCD-aware 1D-grid swizzle.
// R8: MODE-0 epilogue rewritten — old version did 64 scalar 2B global stores
// per thread (V^T: 64 distinct cache lines per wave-store; ~7M L2 write txns
// clogging the VMEM path for all co-resident blocks). New version stages each
// 64-row half-tile in LDS column-major (Ep[col][64], quad-XOR-swizzled
// qpos = q ^ ((col>>3)&7) so Q/K row-gathers and V column-reads are
// bank-spread), then emits fully-coalesced 16B global stores.
// MODE 0: QKV epilogue -> Q[b][h][n][d], K[b][h][n][d], Vt[b][h][d][n] (bf16)
// MODE 1: proj epilogue -> out[row][col]; fp32 when *flag==0, bf16 when 1
template <int MODE, int TMI, int BYL>
__global__ __launch_bounds__(256) void gemm_bt(const bf16* __restrict__ A,
                                               const bf16* __restrict__ Bt,
                                               const bf16* __restrict__ bias,
                                               bf16* __restrict__ O0,
                                               bf16* __restrict__ O1,
                                               bf16* __restrict__ O2,
                                               float* __restrict__ OF,
                                               const int* __restrict__ flag,
                                               int Kdim) {
  constexpr int TM = TMI * 32;
  constexpr int ASZ = 2 * TM * 32;          // A elems, both buffers
  int id = blockIdx.x;
  int xcd = id & 7;
  int j = id >> 3;
  int bx = j / BYL;                       // n-tile (compile-time divisor)
  int by = xcd * BYL + (j % BYL);         // m-tile: same-XCD blocks share A-slab
  int n0 = bx * 128, m0 = by * TM;
  int tid = threadIdx.x, wave = tid >> 6, lane = tid & 63;
  int wm = (wave >> 1) * (TMI * 16), wn = (wave & 1) * 64;
  int cl = lane & 15, qd = lane >> 4;
  __shared__ __align__(16) bf16 sh[ASZ + 2 * 128 * 32];   // As | Bs, reused by epilogue
  floatx4 acc[TMI][4] = {};

  int srow = lane >> 2, sko = (lane & 3) * 8;   // chunk = 16 rows x 32 k = 1024B

  auto stage = [&](int kt, int b) {
#pragma unroll
    for (int i = 0; i < TMI / 2; i++) {
      int c = wave * (TMI / 2) + i;
      int row = c * 16 + srow;
      async16(A + (size_t)(m0 + row) * Kdim + kt + sko,
              (char*)sh + (size_t)b * (TM * 64) + c * 1024);
    }
#pragma unroll
    for (int i = 0; i < 2; i++) {
      int c = wave * 2 + i;
      int row = c * 16 + srow;
      async16(Bt + (size_t)(n0 + row) * Kdim + kt + sko,
              (char*)sh + (size_t)ASZ * 2 + (size_t)b * 8192 + c * 1024);
    }
  };
  auto compute = [&](int b) {
    const bf16* Ab = sh + (size_t)b * (TM * 32);
    const bf16* Bb = sh + ASZ + (size_t)b * (128 * 32);
    bf16x8 af[TMI], bfv[4];
#pragma unroll
    for (int mi = 0; mi < TMI; mi++)
      af[mi] = *(const bf16x8*)(Ab + (wm + mi * 16 + cl) * 32 + qd * 8);
#pragma unroll
    for (int ni = 0; ni < 4; ni++)
      bfv[ni] = *(const bf16x8*)(Bb + (wn + ni * 16 + cl) * 32 + qd * 8);
#pragma unroll
    for (int mi = 0; mi < TMI; mi++)
#pragma unroll
      for (int ni = 0; ni < 4; ni++)
        acc[mi][ni] = __builtin_amdgcn_mfma_f32_16x16x32_bf16(af[mi], bfv[ni],
                                                              acc[mi][ni], 0, 0, 0);
  };

  stage(0, 0);
  for (int kt = 0; kt < Kdim; kt += 64) {
    __syncthreads();                        // buf0 loads drained; prev reads done
    if (kt + 32 < Kdim) stage(kt + 32, 1);  // in flight during compute(0)
    compute(0);
    __syncthreads();                        // buf1 loads drained; buf0 reads done
    if (kt + 64 < Kdim) stage(kt + 64, 0);
    if (kt + 32 < Kdim) compute(1);
  }

  if constexpr (MODE == 0) {
    // -------- coalesced epilogue via LDS transpose (two 64-row halves) -------
    int t = n0 / D_;                   // 0=Q 1=K 2=V (768%128==0 -> uniform)
    int h0 = (n0 % D_) >> 6;           // tile covers heads h0, h0+1
    int b = m0 >> 10;                  // 1024%128==0 -> uniform
    int nbase = m0 & 1023;
    bf16* Ot = (t == 0) ? O0 : O1;
    __syncthreads();                   // all waves done reading As/Bs
#pragma unroll
    for (int hh = 0; hh < 2; hh++) {
      if ((wave >> 1) == hh) {
        // write my 64x64 quadrant, column-major: Ep[col][qpos*4 + r]
#pragma unroll
        for (int ni = 0; ni < 4; ni++) {
          int col = wn + ni * 16 + cl;
          float bv = (float)bias[n0 + col];
          int s = (col >> 3) & 7;
#pragma unroll
          for (int mi = 0; mi < TMI; mi++) {
            int qpos = (mi * 4 + qd) ^ s;
            bf16x4 w = { (bf16)(acc[mi][ni][0] + bv), (bf16)(acc[mi][ni][1] + bv),
                         (bf16)(acc[mi][ni][2] + bv), (bf16)(acc[mi][ni][3] + bv) };
            *(bf16x4*)((char*)sh + col * 144 + qpos * 8) = w;
          }
        }
      }
      __syncthreads();
      if (t < 2) {
        // rows of [b,h,n,d]: 8-lane groups share (head,row), lane jl -> d=jl*8
#pragma unroll
        for (int it = 0; it < 4; it++) {
          int flat = it * 256 + tid;           // 0..1023
          int rh = flat >> 3, jl = flat & 7;
          int hs = rh >> 6, rl = rh & 63;
          int cb = hs * 64 + jl * 8;
          int s = (cb >> 3) & 7;
          int q = rl >> 2, rr = rl & 3;
          bf16x8 w;
#pragma unroll
          for (int jj = 0; jj < 8; jj++)
            w[jj] = *(const bf16*)((char*)sh + (cb + jj) * 144 + ((q ^ s) * 8) + rr * 2);
          int ng = nbase + hh * 64 + rl;
          *(bf16x8*)(Ot + (((size_t)(b * H_ + h0 + hs) * N_ + ng) * DH_ + jl * 8)) = w;
        }
      } else {
        // rows of V^T [b,h,d,n]: 8-lane groups share col(d), lane jl -> n-chunk
#pragma unroll
        for (int it = 0; it < 4; it++) {
          int flat = it * 256 + tid;           // 0..1023
          int col = flat >> 3, jl = flat & 7;
          int hs = col >> 6, d = col & 63;
          int s = (col >> 3) & 7;
          bf16x4 a0 = *(const bf16x4*)((char*)sh + col * 144 + (((2 * jl) ^ s) * 8));
          bf16x4 a1 = *(const bf16x4*)((char*)sh + col * 144 + (((2 * jl + 1) ^ s) * 8));
          bf16x8 w = { a0[0], a0[1], a0[2], a0[3], a1[0], a1[1], a1[2], a1[3] };
          int ng0 = nbase + hh * 64 + jl * 8;
          *(bf16x8*)(O2 + (((size_t)(b * H_ + h0 + hs) * DH_ + d) * N_ + ng0)) = w;
        }
      }
      __syncthreads();
    }
  } else {
    int fbf16 = *flag;
#pragma unroll
    for (int ni = 0; ni < 4; ni++) {
      int colb = n0 + wn + ni * 16;
      float bv = (float)bias[colb + cl];
#pragma unroll
      for (int mi = 0; mi < TMI; mi++) {
#pragma unroll
        for (int r = 0; r < 4; r++) {
          int row = m0 + wm + mi * 16 + qd * 4 + r;
          float v = acc[mi][ni][r] + bv;
          size_t oi = (size_t)row * D_ + colb + cl;
          if (fbf16) O0[oi] = (bf16)v;
          else       OF[oi] = v;
        }
      }
    }
  }
}

// ---------------- fused flash attention, S^T formulation (R6, unchanged) -----
#define KROW 72
#define VROW 136
#define PSTR 136
__global__ __launch_bounds__(256, 4) void attn_k(const bf16* __restrict__ Q,
                                                 const bf16* __restrict__ Kp,
                                                 const bf16* __restrict__ Vt,
                                                 const float* __restrict__ gammaf,
                                                 const bf16* __restrict__ dist,
                                                 bf16* __restrict__ O) {
  int bh = blockIdx.x % (B_ * H_);        // idx%8 == bh%8 -> same-bh same XCD
  int q0 = (blockIdx.x / (B_ * H_)) * 64;
  int b = bh / H_, h = bh % H_;
  int tid = threadIdx.x, wave = tid >> 6, lane = tid & 63;
  int cl = lane & 15, qd = lane >> 4;
  __shared__ __align__(16) bf16 Ks[128 * KROW];   // 18 KB (P slabs alias here)
  __shared__ __align__(16) bf16 Vs[64 * VROW];    // 17 KB

  bf16x8 aq[2];
  {
    const bf16* Qg = Q + ((size_t)bh * N_ + q0 + wave * 16 + cl) * DH_;
    aq[0] = *(const bf16x8*)(Qg + qd * 8);
    aq[1] = *(const bf16x8*)(Qg + 32 + qd * 8);
  }

  floatx4 oacc[4] = {};
  float lsum = 0.f;
  const float LOG2E = 1.4426950408889634f;
  const float SCL = 0.03608439182435161f * LOG2E;   // 768^-0.5 * log2(e)
  float gl = gammaf[b] * LOG2E;

  const bf16* Kg0 = Kp + (size_t)bh * N_ * DH_;
  const bf16* Vg0 = Vt + (size_t)bh * DH_ * N_;
  const bf16* Dg  = dist + (size_t)(q0 + wave * 16 + cl) * N_ + qd * 4;
  int krow = tid >> 1, kh = tid & 1;
  int vrow = tid >> 2, vq = tid & 3;
  bf16* pslab = Ks + wave * 2304;   // 16 rows x PSTR=136 = 2176 <= 2304

  for (int t0 = 0; t0 < N_; t0 += 128) {
    const bf16* Kg = Kg0 + (size_t)(t0 + krow) * DH_ + kh * 32;
    bf16x8 kv[4];
#pragma unroll
    for (int j = 0; j < 4; j++) kv[j] = *(const bf16x8*)(Kg + j * 8);
    const bf16* Vg = Vg0 + (size_t)vrow * N_ + t0 + vq * 8;
    bf16x8 vv[4];
#pragma unroll
    for (int p = 0; p < 4; p++) vv[p] = *(const bf16x8*)(Vg + p * 32);
    bf16x4 ddr[8];
#pragma unroll
    for (int ni = 0; ni < 8; ni++) ddr[ni] = *(const bf16x4*)(Dg + t0 + ni * 16);

    __syncthreads();
#pragma unroll
    for (int j = 0; j < 4; j++)
      *(bf16x8*)(Ks + krow * KROW + kh * 32 + j * 8) = kv[j];
#pragma unroll
    for (int p = 0; p < 4; p++)
      *(bf16x8*)(Vs + vrow * VROW + vq * 8 + p * 32) = vv[p];
    __syncthreads();

    floatx4 sacc[8] = {};
#pragma unroll
    for (int kk = 0; kk < 2; kk++) {
#pragma unroll
      for (int ni = 0; ni < 8; ni++) {
        bf16x8 ak = *(const bf16x8*)(Ks + (ni * 16 + cl) * KROW + kk * 32 + qd * 8);
        sacc[ni] = __builtin_amdgcn_mfma_f32_16x16x32_bf16(ak, aq[kk], sacc[ni], 0, 0, 0);
      }
    }

    bf16x4 pk[8];
#pragma unroll
    for (int ni = 0; ni < 8; ni++) {
#pragma unroll
      for (int r = 0; r < 4; r++) {
        float p = __builtin_exp2f(sacc[ni][r] * SCL - gl * (float)ddr[ni][r]);
        lsum += p;
        pk[ni][r] = (bf16)p;
      }
    }
    __syncthreads();   // all waves done reading Ks before P overwrites it

#pragma unroll
    for (int ni = 0; ni < 8; ni++)
      *(bf16x4*)(pslab + cl * PSTR + ni * 16 + qd * 4) = pk[ni];

#pragma unroll
    for (int kk = 0; kk < 4; kk++) {
      bf16x8 ap = *(const bf16x8*)(pslab + cl * PSTR + kk * 32 + qd * 8);
#pragma unroll
      for (int ni = 0; ni < 4; ni++) {
        bf16x8 bv = *(const bf16x8*)(Vs + (ni * 16 + cl) * VROW + kk * 32 + qd * 8);
        oacc[ni] = __builtin_amdgcn_mfma_f32_16x16x32_bf16(ap, bv, oacc[ni], 0, 0, 0);
      }
    }
  }

  lsum += __shfl_xor(lsum, 16, 64);
  lsum += __shfl_xor(lsum, 32, 64);

#pragma unroll
  for (int r = 0; r < 4; r++) {
    float inv = 1.f / __shfl(lsum, qd * 4 + r, 64);
    int qg = q0 + wave * 16 + qd * 4 + r;
    size_t base = ((size_t)(b * N_ + qg)) * D_ + h * DH_;
#pragma unroll
    for (int ni = 0; ni < 4; ni++)
      O[base + ni * 16 + cl] = (bf16)(oacc[ni][r] * inv);
  }
}

extern "C" void kernel_launch(void* const* d_in, const int* in_sizes, int n_in,
                              void* d_out, int out_size, void* d_ws, size_t ws_size,
                              hipStream_t stream) {
  const void* x     = d_in[0];
  const void* gamma = d_in[1];
  const void* dist  = d_in[2];
  const void* Wqkv  = d_in[3];
  const void* bqkv  = d_in[4];
  const void* Wproj = d_in[5];
  const void* bproj = d_in[6];

  char* ws = (char*)d_ws;
  size_t o = 0;
  int*   flag   = (int*)(ws + o);   o += 16;
  float* gammaf = (float*)(ws + o); o += 32;
  bf16*  xb     = (bf16*)(ws + o);  o += (size_t)M_ * D_ * 2;
  bf16*  distb  = (bf16*)(ws + o);  o += (size_t)N_ * N_ * 2;
  bf16*  bqkvb  = (bf16*)(ws + o);  o += (size_t)D3_ * 2;
  bf16*  bprojb = (bf16*)(ws + o);  o += (size_t)D_ * 2 + 8;
  bf16*  WqkvT  = (bf16*)(ws + o);  o += (size_t)D3_ * D_ * 2;
  bf16*  WprojT = (bf16*)(ws + o);  o += (size_t)D_ * D_ * 2;
  bf16*  Qp     = (bf16*)(ws + o);  o += (size_t)M_ * D_ * 2;
  bf16*  Kp     = (bf16*)(ws + o);  o += (size_t)M_ * D_ * 2;
  bf16*  Vtp    = (bf16*)(ws + o);  o += (size_t)M_ * D_ * 2;
  bf16*  Op     = (bf16*)(ws + o);  o += (size_t)M_ * D_ * 2;
  if (ws_size < o) return;

  detect_small_k<<<1, 256, 0, stream>>>((const unsigned int*)x, bqkv, bproj, gamma,
                                        flag, bqkvb, bprojb, gammaf);
  ingest2_k<<<XBLOCKS + DBLOCKS, 256, 0, stream>>>(x, xb, dist, distb, flag);
  int tilesA = (D3_ / 64) * (D_ / 64);          // 432
  int tilesB = (D_ / 64) * (D_ / 64);           // 144
  ingest_wt_k<<<tilesA + tilesB, 256, 0, stream>>>(Wqkv, WqkvT, Wproj, WprojT,
                                                   flag, tilesA, D3_ / 64);

  // QKV: grid 18 x 64 -> 1D 1152, BYL = 64/8 = 8
  gemm_bt<0, 4, 8><<<18 * 64, 256, 0, stream>>>(
      xb, WqkvT, bqkvb, Qp, Kp, Vtp, nullptr, flag, D_);
  attn_k<<<dim3(B_ * H_ * (N_ / 64)), 256, 0, stream>>>(
      Qp, Kp, Vtp, gammaf, distb, Op);
  // proj: grid 6 x 128 -> 1D 768, BYL = 128/8 = 16
  gemm_bt<1, 2, 16><<<6 * 128, 256, 0, stream>>>(
      Op, WprojT, bprojb, (bf16*)d_out, nullptr, nullptr, (float*)d_out, flag, D_);
}

// Round 2
// 261.217 us; speedup vs baseline: 1.1252x; 1.0295x over previous
//
#include <hip/hip_runtime.h>
#include <hip/hip_bf16.h>
#include <cstdint>
#include <cstddef>

#define B_  8
#define N_  1024
#define D_  768
#define H_  12
#define DH_ 64
#define M_  (B_*N_)     // 8192 rows of X
#define D3_ (3*D_)      // 2304

typedef __bf16 bf16;
typedef __bf16 bf16x4 __attribute__((ext_vector_type(4)));
typedef __bf16 bf16x8 __attribute__((ext_vector_type(8)));
typedef float  floatx4 __attribute__((ext_vector_type(4)));
typedef float  floatx16 __attribute__((ext_vector_type(16)));
typedef unsigned int uint32x4 __attribute__((ext_vector_type(4)));

// async global->LDS, 16B/lane; LDS dest = wave-uniform base + lane*16 (m97/m104)
__device__ __forceinline__ void async16(const void* g, void* l) {
  __builtin_amdgcn_global_load_lds(
      (const __attribute__((address_space(1))) unsigned int*)g,
      (__attribute__((address_space(3))) unsigned int*)l, 16, 0, 0);
}

// ------------- detect dtype (bf16 vs fp32) + ingest small tensors ------------
__global__ __launch_bounds__(256) void detect_small_k(
    const unsigned int* __restrict__ xraw, const void* bq, const void* bp,
    const void* gm, int* __restrict__ flag, bf16* bqd, bf16* bpd, float* gmd) {
  __shared__ int sc;
  if (threadIdx.x == 0) sc = 0;
  __syncthreads();
  int cnt = 0;
  for (int j = 0; j < 8; j++) {
    unsigned int w = xraw[threadIdx.x * 8 + j];
    unsigned int e = (w >> 7) & 0xFF;
    cnt += (e >= 100 && e <= 140) ? 1 : 0;
  }
  atomicAdd(&sc, cnt);
  __syncthreads();
  int f = (sc > 1024) ? 1 : 0;   // bf16 if low-u16 exponents look normal
  if (threadIdx.x == 0) *flag = f;
  for (int i = threadIdx.x; i < D3_; i += 256)
    bqd[i] = f ? ((const bf16*)bq)[i] : (bf16)((const float*)bq)[i];
  for (int i = threadIdx.x; i < D_; i += 256)
    bpd[i] = f ? ((const bf16*)bp)[i] : (bf16)((const float*)bp)[i];
  if (threadIdx.x < B_)
    gmd[threadIdx.x] = f ? (float)((const bf16*)gm)[threadIdx.x]
                         : ((const float*)gm)[threadIdx.x];
}

// ---------- bulk ingest, x + dist in one launch (vectorized x4) --------------
__device__ __forceinline__ void ingest_span(const void* src, bf16* dst, int f,
                                            long n4, long i0, long stride) {
  if (f) {
    const ushort2* s = (const ushort2*)src;
    ushort2* d = (ushort2*)dst;
    for (long i = i0; i < n4 * 2; i += stride) d[i] = s[i];
  } else {
    const float4* s = (const float4*)src;
    for (long i = i0; i < n4; i += stride) {
      float4 v = s[i];
      bf16x4 o = { (bf16)v.x, (bf16)v.y, (bf16)v.z, (bf16)v.w };
      *(bf16x4*)(dst + i * 4) = o;
    }
  }
}
#define XBLOCKS 1024
#define DBLOCKS 256
__global__ __launch_bounds__(256) void ingest2_k(const void* __restrict__ x,
                                                 bf16* __restrict__ xb,
                                                 const void* __restrict__ dist,
                                                 bf16* __restrict__ distb,
                                                 const int* __restrict__ flag) {
  int f = *flag;
  if (blockIdx.x < XBLOCKS) {
    long i0 = (long)blockIdx.x * 256 + threadIdx.x;
    ingest_span(x, xb, f, (long)M_ * D_ / 4, i0, (long)XBLOCKS * 256);
  } else {
    long i0 = (long)(blockIdx.x - XBLOCKS) * 256 + threadIdx.x;
    ingest_span(dist, distb, f, (long)N_ * N_ / 4, i0, (long)DBLOCKS * 256);
  }
}

// ------- tiled ingest+transpose of both weights: src[R][C] -> dst[C][R] ------
__global__ __launch_bounds__(256) void ingest_wt_k(const void* srcA, bf16* dstA,
                                                   const void* srcB, bf16* dstB,
                                                   const int* __restrict__ flag,
                                                   int tilesA, int tcA) {
  __shared__ bf16 t[64][72];
  int f = *flag;
  int bid = blockIdx.x;
  const void* src; bf16* dst; int C;
  int tc;
  if (bid < tilesA) { src = srcA; dst = dstA; C = D3_; tc = tcA; }
  else { bid -= tilesA; src = srcB; dst = dstB; C = D_; tc = D_ / 64; }
  int c0 = (bid % tc) * 64, r0 = (bid / tc) * 64;
  int i = threadIdx.x >> 2, j0 = (threadIdx.x & 3) * 16;
  if (f) {
    const bf16* s = (const bf16*)src + (size_t)(r0 + i) * C + c0 + j0;
#pragma unroll
    for (int jj = 0; jj < 16; jj += 8) *(bf16x8*)&t[i][j0 + jj] = *(const bf16x8*)(s + jj);
  } else {
    const float4* s = (const float4*)((const float*)src + (size_t)(r0 + i) * C + c0 + j0);
#pragma unroll
    for (int jj = 0; jj < 4; jj++) {
      float4 v = s[jj];
      bf16x4 o = { (bf16)v.x, (bf16)v.y, (bf16)v.z, (bf16)v.w };
      *(bf16x4*)&t[i][j0 + jj * 4] = o;
    }
  }
  __syncthreads();
  bf16* d = dst + (size_t)(c0 + i) * D_ + r0 + j0;   // R = D_ always
#pragma unroll
  for (int jj = 0; jj < 16; jj++) d[jj] = t[j0 + jj][i];
}

// ---------------- GEMM: C = A[M][K] * Bt[N][K]^T + bias ----------------------
// R7 double-buffered K-loop + XCD-aware 1D-grid swizzle.
// R8 epilogue: LDS-staged, fully-coalesced 16B stores (Ep[col][64] quad-XOR).
// R9: MODE 0 pre-scales the Q output by SCALE*LOG2E so attn's softmax arg is a
// single fma (saves one VALU mul per S-element in the attn hot loop).
// MODE 0: QKV epilogue -> Q[b][h][n][d] (pre-scaled), K[b][h][n][d], Vt[b][h][d][n]
// MODE 1: proj epilogue -> out[row][col]; fp32 when *flag==0, bf16 when 1
template <int MODE, int TMI, int BYL>
__global__ __launch_bounds__(256) void gemm_bt(const bf16* __restrict__ A,
                                               const bf16* __restrict__ Bt,
                                               const bf16* __restrict__ bias,
                                               bf16* __restrict__ O0,
                                               bf16* __restrict__ O1,
                                               bf16* __restrict__ O2,
                                               float* __restrict__ OF,
                                               const int* __restrict__ flag,
                                               int Kdim) {
  constexpr int TM = TMI * 32;
  constexpr int ASZ = 2 * TM * 32;          // A elems, both buffers
  int id = blockIdx.x;
  int xcd = id & 7;
  int j = id >> 3;
  int bx = j / BYL;                       // n-tile (compile-time divisor)
  int by = xcd * BYL + (j % BYL);         // m-tile: same-XCD blocks share A-slab
  int n0 = bx * 128, m0 = by * TM;
  int tid = threadIdx.x, wave = tid >> 6, lane = tid & 63;
  int wm = (wave >> 1) * (TMI * 16), wn = (wave & 1) * 64;
  int cl = lane & 15, qd = lane >> 4;
  __shared__ __align__(16) bf16 sh[ASZ + 2 * 128 * 32];   // As | Bs, reused by epilogue
  floatx4 acc[TMI][4] = {};

  int srow = lane >> 2, sko = (lane & 3) * 8;   // chunk = 16 rows x 32 k = 1024B

  auto stage = [&](int kt, int b) {
#pragma unroll
    for (int i = 0; i < TMI / 2; i++) {
      int c = wave * (TMI / 2) + i;
      int row = c * 16 + srow;
      async16(A + (size_t)(m0 + row) * Kdim + kt + sko,
              (char*)sh + (size_t)b * (TM * 64) + c * 1024);
    }
#pragma unroll
    for (int i = 0; i < 2; i++) {
      int c = wave * 2 + i;
      int row = c * 16 + srow;
      async16(Bt + (size_t)(n0 + row) * Kdim + kt + sko,
              (char*)sh + (size_t)ASZ * 2 + (size_t)b * 8192 + c * 1024);
    }
  };
  auto compute = [&](int b) {
    const bf16* Ab = sh + (size_t)b * (TM * 32);
    const bf16* Bb = sh + ASZ + (size_t)b * (128 * 32);
    bf16x8 af[TMI], bfv[4];
#pragma unroll
    for (int mi = 0; mi < TMI; mi++)
      af[mi] = *(const bf16x8*)(Ab + (wm + mi * 16 + cl) * 32 + qd * 8);
#pragma unroll
    for (int ni = 0; ni < 4; ni++)
      bfv[ni] = *(const bf16x8*)(Bb + (wn + ni * 16 + cl) * 32 + qd * 8);
#pragma unroll
    for (int mi = 0; mi < TMI; mi++)
#pragma unroll
      for (int ni = 0; ni < 4; ni++)
        acc[mi][ni] = __builtin_amdgcn_mfma_f32_16x16x32_bf16(af[mi], bfv[ni],
                                                              acc[mi][ni], 0, 0, 0);
  };

  stage(0, 0);
  for (int kt = 0; kt < Kdim; kt += 64) {
    __syncthreads();                        // buf0 loads drained; prev reads done
    if (kt + 32 < Kdim) stage(kt + 32, 1);  // in flight during compute(0)
    compute(0);
    __syncthreads();                        // buf1 loads drained; buf0 reads done
    if (kt + 64 < Kdim) stage(kt + 64, 0);
    if (kt + 32 < Kdim) compute(1);
  }

  if constexpr (MODE == 0) {
    // -------- coalesced epilogue via LDS transpose (two 64-row halves) -------
    int t = n0 / D_;                   // 0=Q 1=K 2=V (768%128==0 -> uniform)
    int h0 = (n0 % D_) >> 6;           // tile covers heads h0, h0+1
    int b = m0 >> 10;                  // 1024%128==0 -> uniform
    int nbase = m0 & 1023;
    bf16* Ot = (t == 0) ? O0 : O1;
    float qs = (t == 0) ? (0.03608439182435161f * 1.4426950408889634f) : 1.f;
    __syncthreads();                   // all waves done reading As/Bs
#pragma unroll
    for (int hh = 0; hh < 2; hh++) {
      if ((wave >> 1) == hh) {
        // write my 64x64 quadrant, column-major: Ep[col][qpos*4 + r]
#pragma unroll
        for (int ni = 0; ni < 4; ni++) {
          int col = wn + ni * 16 + cl;
          float bv = (float)bias[n0 + col];
          int s = (col >> 3) & 7;
#pragma unroll
          for (int mi = 0; mi < TMI; mi++) {
            int qpos = (mi * 4 + qd) ^ s;
            bf16x4 w = { (bf16)((acc[mi][ni][0] + bv) * qs),
                         (bf16)((acc[mi][ni][1] + bv) * qs),
                         (bf16)((acc[mi][ni][2] + bv) * qs),
                         (bf16)((acc[mi][ni][3] + bv) * qs) };
            *(bf16x4*)((char*)sh + col * 144 + qpos * 8) = w;
          }
        }
      }
      __syncthreads();
      if (t < 2) {
        // rows of [b,h,n,d]: 8-lane groups share (head,row), lane jl -> d=jl*8
#pragma unroll
        for (int it = 0; it < 4; it++) {
          int flat = it * 256 + tid;           // 0..1023
          int rh = flat >> 3, jl = flat & 7;
          int hs = rh >> 6, rl = rh & 63;
          int cb = hs * 64 + jl * 8;
          int s = (cb >> 3) & 7;
          int q = rl >> 2, rr = rl & 3;
          bf16x8 w;
#pragma unroll
          for (int jj = 0; jj < 8; jj++)
            w[jj] = *(const bf16*)((char*)sh + (cb + jj) * 144 + ((q ^ s) * 8) + rr * 2);
          int ng = nbase + hh * 64 + rl;
          *(bf16x8*)(Ot + (((size_t)(b * H_ + h0 + hs) * N_ + ng) * DH_ + jl * 8)) = w;
        }
      } else {
        // rows of V^T [b,h,d,n]: 8-lane groups share col(d), lane jl -> n-chunk
#pragma unroll
        for (int it = 0; it < 4; it++) {
          int flat = it * 256 + tid;           // 0..1023
          int col = flat >> 3, jl = flat & 7;
          int hs = col >> 6, d = col & 63;
          int s = (col >> 3) & 7;
          bf16x4 a0 = *(const bf16x4*)((char*)sh + col * 144 + (((2 * jl) ^ s) * 8));
          bf16x4 a1 = *(const bf16x4*)((char*)sh + col * 144 + (((2 * jl + 1) ^ s) * 8));
          bf16x8 w = { a0[0], a0[1], a0[2], a0[3], a1[0], a1[1], a1[2], a1[3] };
          int ng0 = nbase + hh * 64 + jl * 8;
          *(bf16x8*)(O2 + (((size_t)(b * H_ + h0 + hs) * DH_ + d) * N_ + ng0)) = w;
        }
      }
      __syncthreads();
    }
  } else {
    int fbf16 = *flag;
#pragma unroll
    for (int ni = 0; ni < 4; ni++) {
      int colb = n0 + wn + ni * 16;
      float bv = (float)bias[colb + cl];
#pragma unroll
      for (int mi = 0; mi < TMI; mi++) {
#pragma unroll
        for (int r = 0; r < 4; r++) {
          int row = m0 + wm + mi * 16 + qd * 4 + r;
          float v = acc[mi][ni][r] + bv;
          size_t oi = (size_t)row * D_ + colb + cl;
          if (fbf16) O0[oi] = (bf16)v;
          else       OF[oi] = v;
        }
      }
    }
  }
}

// ---------------- fused flash attention, R9: 32x32 MFMA + in-register P -----
// Swapped QK^T (mfma(K,Q)) -> lane holds S^T column for q=lane&31; softmax in
// registers; v_cvt_pk_bf16_f32 + v_permlane32_swap_b32 rebuild the PV A-frag
// in-register (no P LDS round-trip, no 3rd barrier). Wave owns 32 q-rows.
// K/V staged in LDS with XOR swizzle (slot ^= row&7) via reg-staging.
// Q arrives PRE-SCALED by SCALE*LOG2E from the QKV epilogue.
__global__ __launch_bounds__(256, 3) void attn_k(const bf16* __restrict__ Q,
                                                 const bf16* __restrict__ Kp,
                                                 const bf16* __restrict__ Vt,
                                                 const float* __restrict__ gammaf,
                                                 const bf16* __restrict__ dist,
                                                 bf16* __restrict__ O) {
  int bh = blockIdx.x % (B_ * H_);        // idx%8 == bh%8 -> same-bh same XCD
  int q0 = (blockIdx.x / (B_ * H_)) * 128;
  int b = bh / H_, h = bh % H_;
  int tid = threadIdx.x, wave = tid >> 6, lane = tid & 63;
  int l5 = lane & 31, hh = lane >> 5, l7 = lane & 7;
  __shared__ __align__(16) bf16 Ks[128 * 64];   // [token][d], 16B slots XOR row&7
  __shared__ __align__(16) bf16 Vs[64 * 128];   // [d][token], 16B slots XOR row&7
  __shared__ float Ls[4 * 32];                  // per-wave 1/lsum slab

  // Q B-fragments: row = q (lane&31), k-elems d = st*16 + hh*8 + j
  bf16x8 aq[4];
  {
    const bf16* Qg = Q + ((size_t)bh * N_ + q0 + wave * 32 + l5) * DH_ + hh * 8;
#pragma unroll
    for (int st = 0; st < 4; st++) aq[st] = *(const bf16x8*)(Qg + st * 16);
  }

  floatx16 oacc[2] = {};
  float lsum = 0.f;
  const float LOG2E = 1.4426950408889634f;
  float gl = gammaf[b] * LOG2E;

  const bf16* Kg0 = Kp + (size_t)bh * N_ * DH_;
  const bf16* Vg0 = Vt + (size_t)bh * DH_ * N_;
  const bf16* Dg  = dist + (size_t)(q0 + wave * 32 + l5) * N_ + hh * 4;

  // staging: thread t owns 4 K-slots (id>>3 = row, id&7 = slot) and 4 V-slots
  // (id>>4 = row, id&15 = slot); LDS position swizzled, global linear.
  int kofs[4], vofs[4];
  const bf16* kg[4]; const bf16* vg[4];
#pragma unroll
  for (int i = 0; i < 4; i++) {
    int id = tid + i * 256;
    int kr = id >> 3, ksl = id & 7;
    kofs[i] = kr * 128 + ((ksl ^ (kr & 7)) * 16);
    kg[i] = Kg0 + (size_t)kr * DH_ + ksl * 8;
    int vr = id >> 4, vsl = id & 15;
    vofs[i] = vr * 256 + ((vsl ^ (vr & 7)) * 16);
    vg[i] = Vg0 + (size_t)vr * N_ + vsl * 8;
  }
  int krd = l5 * 128;     // + sub*4096 + ((st*2+hh)^l7)*16
  int vrd = l5 * 256;     // + t*8192  + ((sub*4+kk*2+hh)^l7)*16

  for (int t0 = 0; t0 < N_; t0 += 128) {
    // issue all global loads for this tile (latency overlaps barrier wait)
    bf16x8 kv[4], vv[4];
#pragma unroll
    for (int i = 0; i < 4; i++) kv[i] = *(const bf16x8*)(kg[i] + (size_t)t0 * DH_);
#pragma unroll
    for (int i = 0; i < 4; i++) vv[i] = *(const bf16x8*)(vg[i] + t0);
    bf16x4 ddr[16];       // dist in the C/D k-pattern: k = (r&3)+8*(r>>2)+4*hh
#pragma unroll
    for (int sub = 0; sub < 4; sub++)
#pragma unroll
      for (int jj = 0; jj < 4; jj++)
        ddr[sub * 4 + jj] = *(const bf16x4*)(Dg + t0 + sub * 32 + jj * 8);

    __syncthreads();      // all waves done reading Ks/Vs of previous tile
#pragma unroll
    for (int i = 0; i < 4; i++) *(bf16x8*)((char*)Ks + kofs[i]) = kv[i];
#pragma unroll
    for (int i = 0; i < 4; i++) *(bf16x8*)((char*)Vs + vofs[i]) = vv[i];
    __syncthreads();      // tile visible

#pragma unroll
    for (int sub = 0; sub < 4; sub++) {
      // S^T subtile: D[m=token][n=q], reduction over d (4 x K=16)
      floatx16 s = {};
      __builtin_amdgcn_s_setprio(1);
#pragma unroll
      for (int st = 0; st < 4; st++) {
        bf16x8 ak = *(const bf16x8*)((char*)Ks + sub * 4096 + krd +
                                     (((st * 2 + hh) ^ l7) * 16));
        s = __builtin_amdgcn_mfma_f32_32x32x16_bf16(ak, aq[st], s, 0, 0, 0);
      }
      __builtin_amdgcn_s_setprio(0);

      // softmax on 16 in-register values (Q pre-scaled: arg = s - gl*d)
      float p[16];
#pragma unroll
      for (int r = 0; r < 16; r++) {
        float df = (float)ddr[sub * 4 + (r >> 2)][r & 3];
        p[r] = __builtin_exp2f(__builtin_fmaf(-gl, df, s[r]));
        lsum += p[r];
      }
      // pack pairs -> bf16 words; permlane32_swap: a'=[a_lo|b_lo], b'=[a_hi|b_hi]
      unsigned pw[8];
#pragma unroll
      for (int i = 0; i < 8; i++) {
        unsigned o_;
        asm("v_cvt_pk_bf16_f32 %0, %1, %2"
            : "=v"(o_) : "v"(p[2 * i]), "v"(p[2 * i + 1]));
        pw[i] = o_;
      }
      asm("v_permlane32_swap_b32 %0, %1" : "+v"(pw[0]), "+v"(pw[2]));
      asm("v_permlane32_swap_b32 %0, %1" : "+v"(pw[1]), "+v"(pw[3]));
      asm("v_permlane32_swap_b32 %0, %1" : "+v"(pw[4]), "+v"(pw[6]));
      asm("v_permlane32_swap_b32 %0, %1" : "+v"(pw[5]), "+v"(pw[7]));
      bf16x8 pa0, pa1;    // A-frags: A[q=lane&31][k = kk*16 + hh*8 + j]
      { uint32x4 u0 = { pw[0], pw[1], pw[2], pw[3] }; pa0 = *(bf16x8*)&u0; }
      { uint32x4 u1 = { pw[4], pw[5], pw[6], pw[7] }; pa1 = *(bf16x8*)&u1; }

      __builtin_amdgcn_s_setprio(1);
#pragma unroll
      for (int t = 0; t < 2; t++) {
        bf16x8 bv0 = *(const bf16x8*)((char*)Vs + t * 8192 + vrd +
                                      (((sub * 4 + hh) ^ l7) * 16));
        oacc[t] = __builtin_amdgcn_mfma_f32_32x32x16_bf16(pa0, bv0, oacc[t], 0, 0, 0);
        bf16x8 bv1 = *(const bf16x8*)((char*)Vs + t * 8192 + vrd +
                                      (((sub * 4 + 2 + hh) ^ l7) * 16));
        oacc[t] = __builtin_amdgcn_mfma_f32_32x32x16_bf16(pa1, bv1, oacc[t], 0, 0, 0);
      }
      __builtin_amdgcn_s_setprio(0);
    }
  }

  // lsum(q) = lo-half + hi-half partial sums; broadcast 1/lsum via LDS slab
  lsum += __shfl_xor(lsum, 32, 64);
  float inv = 1.f / lsum;
  Ls[wave * 32 + l5] = inv;         // lanes l, l+32 write same value: benign
  __syncthreads();
  size_t obase = ((size_t)b * N_ + q0 + wave * 32) * D_ + h * DH_;
#pragma unroll
  for (int r = 0; r < 16; r++) {
    int qrow = (r & 3) + 8 * (r >> 2) + 4 * hh;
    float iv = Ls[wave * 32 + qrow];
#pragma unroll
    for (int t = 0; t < 2; t++)
      O[obase + (size_t)qrow * D_ + t * 32 + l5] = (bf16)(oacc[t][r] * iv);
  }
}

extern "C" void kernel_launch(void* const* d_in, const int* in_sizes, int n_in,
                              void* d_out, int out_size, void* d_ws, size_t ws_size,
                              hipStream_t stream) {
  const void* x     = d_in[0];
  const void* gamma = d_in[1];
  const void* dist  = d_in[2];
  const void* Wqkv  = d_in[3];
  const void* bqkv  = d_in[4];
  const void* Wproj = d_in[5];
  const void* bproj = d_in[6];

  char* ws = (char*)d_ws;
  size_t o = 0;
  int*   flag   = (int*)(ws + o);   o += 16;
  float* gammaf = (float*)(ws + o); o += 32;
  bf16*  xb     = (bf16*)(ws + o);  o += (size_t)M_ * D_ * 2;
  bf16*  distb  = (bf16*)(ws + o);  o += (size_t)N_ * N_ * 2;
  bf16*  bqkvb  = (bf16*)(ws + o);  o += (size_t)D3_ * 2;
  bf16*  bprojb = (bf16*)(ws + o);  o += (size_t)D_ * 2 + 8;
  bf16*  WqkvT  = (bf16*)(ws + o);  o += (size_t)D3_ * D_ * 2;
  bf16*  WprojT = (bf16*)(ws + o);  o += (size_t)D_ * D_ * 2;
  bf16*  Qp     = (bf16*)(ws + o);  o += (size_t)M_ * D_ * 2;
  bf16*  Kp     = (bf16*)(ws + o);  o += (size_t)M_ * D_ * 2;
  bf16*  Vtp    = (bf16*)(ws + o);  o += (size_t)M_ * D_ * 2;
  bf16*  Op     = (bf16*)(ws + o);  o += (size_t)M_ * D_ * 2;
  if (ws_size < o) return;

  detect_small_k<<<1, 256, 0, stream>>>((const unsigned int*)x, bqkv, bproj, gamma,
                                        flag, bqkvb, bprojb, gammaf);
  ingest2_k<<<XBLOCKS + DBLOCKS, 256, 0, stream>>>(x, xb, dist, distb, flag);
  int tilesA = (D3_ / 64) * (D_ / 64);          // 432
  int tilesB = (D_ / 64) * (D_ / 64);           // 144
  ingest_wt_k<<<tilesA + tilesB, 256, 0, stream>>>(Wqkv, WqkvT, Wproj, WprojT,
                                                   flag, tilesA, D3_ / 64);

  // QKV: grid 18 x 64 -> 1D 1152, BYL = 64/8 = 8
  gemm_bt<0, 4, 8><<<18 * 64, 256, 0, stream>>>(
      xb, WqkvT, bqkvb, Qp, Kp, Vtp, nullptr, flag, D_);
  attn_k<<<dim3(B_ * H_ * (N_ / 128)), 256, 0, stream>>>(
      Qp, Kp, Vtp, gammaf, distb, Op);
  // proj: grid 6 x 128 -> 1D 768, BYL = 128/8 = 16
  gemm_bt<1, 2, 16><<<6 * 128, 256, 0, stream>>>(
      Op, WprojT, bprojb, (bf16*)d_out, nullptr, nullptr, (float*)d_out, flag, D_);
}

// Round 3
// 249.468 us; speedup vs baseline: 1.1782x; 1.0471x over previous
//
#include <hip/hip_runtime.h>
#include <hip/hip_bf16.h>
#include <cstdint>
#include <cstddef>

#define B_  8
#define N_  1024
#define D_  768
#define H_  12
#define DH_ 64
#define M_  (B_*N_)     // 8192 rows of X
#define D3_ (3*D_)      // 2304

typedef __bf16 bf16;
typedef __bf16 bf16x4 __attribute__((ext_vector_type(4)));
typedef __bf16 bf16x8 __attribute__((ext_vector_type(8)));
typedef float  floatx4 __attribute__((ext_vector_type(4)));
typedef float  floatx16 __attribute__((ext_vector_type(16)));
typedef unsigned int uint32x4 __attribute__((ext_vector_type(4)));

// async global->LDS, 16B/lane; LDS dest = wave-uniform base + lane*16 (m97/m104)
__device__ __forceinline__ void async16(const void* g, void* l) {
  __builtin_amdgcn_global_load_lds(
      (const __attribute__((address_space(1))) unsigned int*)g,
      (__attribute__((address_space(3))) unsigned int*)l, 16, 0, 0);
}

template <int Ncnt> __device__ __forceinline__ void wait_vmcnt() {
  asm volatile("s_waitcnt vmcnt(%0)" :: "n"(Ncnt) : "memory");
}

// ------------- detect dtype (bf16 vs fp32) + ingest small tensors ------------
__global__ __launch_bounds__(256) void detect_small_k(
    const unsigned int* __restrict__ xraw, const void* bq, const void* bp,
    const void* gm, int* __restrict__ flag, bf16* bqd, bf16* bpd, float* gmd) {
  __shared__ int sc;
  if (threadIdx.x == 0) sc = 0;
  __syncthreads();
  int cnt = 0;
  for (int j = 0; j < 8; j++) {
    unsigned int w = xraw[threadIdx.x * 8 + j];
    unsigned int e = (w >> 7) & 0xFF;
    cnt += (e >= 100 && e <= 140) ? 1 : 0;
  }
  atomicAdd(&sc, cnt);
  __syncthreads();
  int f = (sc > 1024) ? 1 : 0;   // bf16 if low-u16 exponents look normal
  if (threadIdx.x == 0) *flag = f;
  for (int i = threadIdx.x; i < D3_; i += 256)
    bqd[i] = f ? ((const bf16*)bq)[i] : (bf16)((const float*)bq)[i];
  for (int i = threadIdx.x; i < D_; i += 256)
    bpd[i] = f ? ((const bf16*)bp)[i] : (bf16)((const float*)bp)[i];
  if (threadIdx.x < B_)
    gmd[threadIdx.x] = f ? (float)((const bf16*)gm)[threadIdx.x]
                         : ((const float*)gm)[threadIdx.x];
}

// ---------- bulk ingest, x + dist in one launch (vectorized x4) --------------
__device__ __forceinline__ void ingest_span(const void* src, bf16* dst, int f,
                                            long n4, long i0, long stride) {
  if (f) {
    const ushort2* s = (const ushort2*)src;
    ushort2* d = (ushort2*)dst;
    for (long i = i0; i < n4 * 2; i += stride) d[i] = s[i];
  } else {
    const float4* s = (const float4*)src;
    for (long i = i0; i < n4; i += stride) {
      float4 v = s[i];
      bf16x4 o = { (bf16)v.x, (bf16)v.y, (bf16)v.z, (bf16)v.w };
      *(bf16x4*)(dst + i * 4) = o;
    }
  }
}
#define XBLOCKS 1024
#define DBLOCKS 256
__global__ __launch_bounds__(256) void ingest2_k(const void* __restrict__ x,
                                                 bf16* __restrict__ xb,
                                                 const void* __restrict__ dist,
                                                 bf16* __restrict__ distb,
                                                 const int* __restrict__ flag) {
  int f = *flag;
  if (blockIdx.x < XBLOCKS) {
    long i0 = (long)blockIdx.x * 256 + threadIdx.x;
    ingest_span(x, xb, f, (long)M_ * D_ / 4, i0, (long)XBLOCKS * 256);
  } else {
    long i0 = (long)(blockIdx.x - XBLOCKS) * 256 + threadIdx.x;
    ingest_span(dist, distb, f, (long)N_ * N_ / 4, i0, (long)DBLOCKS * 256);
  }
}

// ------- tiled ingest+transpose of both weights: src[R][C] -> dst[C][R] ------
__global__ __launch_bounds__(256) void ingest_wt_k(const void* srcA, bf16* dstA,
                                                   const void* srcB, bf16* dstB,
                                                   const int* __restrict__ flag,
                                                   int tilesA, int tcA) {
  __shared__ bf16 t[64][72];
  int f = *flag;
  int bid = blockIdx.x;
  const void* src; bf16* dst; int C;
  int tc;
  if (bid < tilesA) { src = srcA; dst = dstA; C = D3_; tc = tcA; }
  else { bid -= tilesA; src = srcB; dst = dstB; C = D_; tc = D_ / 64; }
  int c0 = (bid % tc) * 64, r0 = (bid / tc) * 64;
  int i = threadIdx.x >> 2, j0 = (threadIdx.x & 3) * 16;
  if (f) {
    const bf16* s = (const bf16*)src + (size_t)(r0 + i) * C + c0 + j0;
#pragma unroll
    for (int jj = 0; jj < 16; jj += 8) *(bf16x8*)&t[i][j0 + jj] = *(const bf16x8*)(s + jj);
  } else {
    const float4* s = (const float4*)((const float*)src + (size_t)(r0 + i) * C + c0 + j0);
#pragma unroll
    for (int jj = 0; jj < 4; jj++) {
      float4 v = s[jj];
      bf16x4 o = { (bf16)v.x, (bf16)v.y, (bf16)v.z, (bf16)v.w };
      *(bf16x4*)&t[i][j0 + jj * 4] = o;
    }
  }
  __syncthreads();
  bf16* d = dst + (size_t)(c0 + i) * D_ + r0 + j0;   // R = D_ always
#pragma unroll
  for (int jj = 0; jj < 16; jj++) d[jj] = t[j0 + jj][i];
}

// ---------------- GEMM: C = A[M][K] * Bt[N][K]^T + bias ----------------------
// R10: 4-buffer depth-3 counted-vmcnt pipeline (T3+T4). One raw s_barrier per
// 32-K step; s_waitcnt vmcnt(2*LPW) keeps 2 K-tiles of global_load_lds in
// flight ACROSS the barrier (never drains to 0 in the main loop; tail
// LPW -> 0). T2: 16B-slot XOR swizzle (slot ^= (row>>1)&3) applied on the
// GLOBAL source (linear LDS dest, rule #21) and on fragment reads: 8-way
// bank conflict -> 2-way (free). T5: setprio around the MFMA cluster.
// R8 epilogue (MODE 0): LDS-staged coalesced stores. R9: Q pre-scaled.
// MODE 0: QKV -> Q[b][h][n][d] (pre-scaled), K[b][h][n][d], Vt[b][h][d][n]
// MODE 1: proj -> out[row][col]; fp32 when *flag==0, bf16 when 1
template <int MODE, int TMI, int BYL>
__global__ __launch_bounds__(256) void gemm_bt(const bf16* __restrict__ A,
                                               const bf16* __restrict__ Bt,
                                               const bf16* __restrict__ bias,
                                               bf16* __restrict__ O0,
                                               bf16* __restrict__ O1,
                                               bf16* __restrict__ O2,
                                               float* __restrict__ OF,
                                               const int* __restrict__ flag,
                                               int Kdim) {
  constexpr int TM = TMI * 32;
  constexpr int NBUF = 4;
  constexpr int LPW = TMI / 2 + 2;          // async16 per wave per K-tile
  constexpr int AELEM = NBUF * TM * 32;     // A elems, all buffers
  int id = blockIdx.x;
  int xcd = id & 7;
  int j = id >> 3;
  int bx = j / BYL;                       // n-tile (compile-time divisor)
  int by = xcd * BYL + (j % BYL);         // m-tile: same-XCD blocks share A-slab
  int n0 = bx * 128, m0 = by * TM;
  int tid = threadIdx.x, wave = tid >> 6, lane = tid & 63;
  int wm = (wave >> 1) * (TMI * 16), wn = (wave & 1) * 64;
  int cl = lane & 15, qd = lane >> 4;
  __shared__ __align__(16) bf16 sh[AELEM + NBUF * 128 * 32];
  floatx4 acc[TMI][4] = {};

  int srow = lane >> 2;                           // row within 16-row chunk
  int sko = ((lane & 3) ^ ((srow >> 1) & 3)) * 8; // swizzled 16B slot (T2)

  auto stage = [&](int tk, int buf) {
    int kt = tk * 32;
#pragma unroll
    for (int i = 0; i < TMI / 2; i++) {
      int c = wave * (TMI / 2) + i;
      int row = c * 16 + srow;
      async16(A + (size_t)(m0 + row) * Kdim + kt + sko,
              (char*)sh + buf * (TM * 64) + c * 1024);
    }
#pragma unroll
    for (int i = 0; i < 2; i++) {
      int c = wave * 2 + i;
      int row = c * 16 + srow;
      async16(Bt + (size_t)(n0 + row) * Kdim + kt + sko,
              (char*)sh + (size_t)AELEM * 2 + buf * 8192 + c * 1024);
    }
  };
  auto compute = [&](int buf) {
    const bf16* Ab = sh + buf * (TM * 32);
    const bf16* Bb = sh + AELEM + buf * (128 * 32);
    int ga = (cl >> 1) & 3;                 // read-side swizzle (T2)
    bf16x8 af[TMI], bfv[4];
#pragma unroll
    for (int mi = 0; mi < TMI; mi++)
      af[mi] = *(const bf16x8*)(Ab + (wm + mi * 16 + cl) * 32 + ((qd ^ ga) * 8));
#pragma unroll
    for (int ni = 0; ni < 4; ni++)
      bfv[ni] = *(const bf16x8*)(Bb + (wn + ni * 16 + cl) * 32 + ((qd ^ ga) * 8));
    __builtin_amdgcn_s_setprio(1);
#pragma unroll
    for (int mi = 0; mi < TMI; mi++)
#pragma unroll
      for (int ni = 0; ni < 4; ni++)
        acc[mi][ni] = __builtin_amdgcn_mfma_f32_16x16x32_bf16(af[mi], bfv[ni],
                                                              acc[mi][ni], 0, 0, 0);
    __builtin_amdgcn_s_setprio(0);
  };

  int NT = Kdim >> 5;                       // 32-wide K-tiles (768 -> 24)
  stage(0, 0); stage(1, 1); stage(2, 2);    // depth-3 prologue
  for (int t = 0; t < NT - 3; ++t) {
    wait_vmcnt<2 * LPW>();                  // oldest tile landed (mine)
    __builtin_amdgcn_sched_barrier(0);
    __builtin_amdgcn_s_barrier();           // everyone's share landed
    stage(t + 3, (t + 3) & 3);              // overwrites slot read at t-1
    compute(t & 3);
  }
  wait_vmcnt<2 * LPW>();
  __builtin_amdgcn_sched_barrier(0);
  __builtin_amdgcn_s_barrier();
  compute((NT - 3) & 3);
  wait_vmcnt<LPW>();
  __builtin_amdgcn_sched_barrier(0);
  __builtin_amdgcn_s_barrier();
  compute((NT - 2) & 3);
  wait_vmcnt<0>();
  __builtin_amdgcn_sched_barrier(0);
  __builtin_amdgcn_s_barrier();
  compute((NT - 1) & 3);

  if constexpr (MODE == 0) {
    // -------- coalesced epilogue via LDS transpose (two 64-row halves) -------
    int t = n0 / D_;                   // 0=Q 1=K 2=V (768%128==0 -> uniform)
    int h0 = (n0 % D_) >> 6;           // tile covers heads h0, h0+1
    int b = m0 >> 10;                  // 1024%128==0 -> uniform
    int nbase = m0 & 1023;
    bf16* Ot = (t == 0) ? O0 : O1;
    float qs = (t == 0) ? (0.03608439182435161f * 1.4426950408889634f) : 1.f;
    __syncthreads();                   // all waves done reading As/Bs
#pragma unroll
    for (int hh = 0; hh < 2; hh++) {
      if ((wave >> 1) == hh) {
        // write my 64x64 quadrant, column-major: Ep[col][qpos*4 + r]
#pragma unroll
        for (int ni = 0; ni < 4; ni++) {
          int col = wn + ni * 16 + cl;
          float bv = (float)bias[n0 + col];
          int s = (col >> 3) & 7;
#pragma unroll
          for (int mi = 0; mi < TMI; mi++) {
            int qpos = (mi * 4 + qd) ^ s;
            bf16x4 w = { (bf16)((acc[mi][ni][0] + bv) * qs),
                         (bf16)((acc[mi][ni][1] + bv) * qs),
                         (bf16)((acc[mi][ni][2] + bv) * qs),
                         (bf16)((acc[mi][ni][3] + bv) * qs) };
            *(bf16x4*)((char*)sh + col * 144 + qpos * 8) = w;
          }
        }
      }
      __syncthreads();
      if (t < 2) {
        // rows of [b,h,n,d]: 8-lane groups share (head,row), lane jl -> d=jl*8
#pragma unroll
        for (int it = 0; it < 4; it++) {
          int flat = it * 256 + tid;           // 0..1023
          int rh = flat >> 3, jl = flat & 7;
          int hs = rh >> 6, rl = rh & 63;
          int cb = hs * 64 + jl * 8;
          int s = (cb >> 3) & 7;
          int q = rl >> 2, rr = rl & 3;
          bf16x8 w;
#pragma unroll
          for (int jj = 0; jj < 8; jj++)
            w[jj] = *(const bf16*)((char*)sh + (cb + jj) * 144 + ((q ^ s) * 8) + rr * 2);
          int ng = nbase + hh * 64 + rl;
          *(bf16x8*)(Ot + (((size_t)(b * H_ + h0 + hs) * N_ + ng) * DH_ + jl * 8)) = w;
        }
      } else {
        // rows of V^T [b,h,d,n]: 8-lane groups share col(d), lane jl -> n-chunk
#pragma unroll
        for (int it = 0; it < 4; it++) {
          int flat = it * 256 + tid;           // 0..1023
          int col = flat >> 3, jl = flat & 7;
          int hs = col >> 6, d = col & 63;
          int s = (col >> 3) & 7;
          bf16x4 a0 = *(const bf16x4*)((char*)sh + col * 144 + (((2 * jl) ^ s) * 8));
          bf16x4 a1 = *(const bf16x4*)((char*)sh + col * 144 + (((2 * jl + 1) ^ s) * 8));
          bf16x8 w = { a0[0], a0[1], a0[2], a0[3], a1[0], a1[1], a1[2], a1[3] };
          int ng0 = nbase + hh * 64 + jl * 8;
          *(bf16x8*)(O2 + (((size_t)(b * H_ + h0 + hs) * DH_ + d) * N_ + ng0)) = w;
        }
      }
      __syncthreads();
    }
  } else {
    int fbf16 = *flag;
#pragma unroll
    for (int ni = 0; ni < 4; ni++) {
      int colb = n0 + wn + ni * 16;
      float bv = (float)bias[colb + cl];
#pragma unroll
      for (int mi = 0; mi < TMI; mi++) {
#pragma unroll
        for (int r = 0; r < 4; r++) {
          int row = m0 + wm + mi * 16 + qd * 4 + r;
          float v = acc[mi][ni][r] + bv;
          size_t oi = (size_t)row * D_ + colb + cl;
          if (fbf16) O0[oi] = (bf16)v;
          else       OF[oi] = v;
        }
      }
    }
  }
}

// ---------------- fused flash attention, R9: 32x32 MFMA + in-register P -----
// Swapped QK^T (mfma(K,Q)) -> lane holds S^T column for q=lane&31; softmax in
// registers; v_cvt_pk_bf16_f32 + v_permlane32_swap_b32 rebuild the PV A-frag
// in-register (no P LDS round-trip, no 3rd barrier). Wave owns 32 q-rows.
// K/V staged in LDS with XOR swizzle (slot ^= row&7) via reg-staging.
// Q arrives PRE-SCALED by SCALE*LOG2E from the QKV epilogue.
__global__ __launch_bounds__(256, 3) void attn_k(const bf16* __restrict__ Q,
                                                 const bf16* __restrict__ Kp,
                                                 const bf16* __restrict__ Vt,
                                                 const float* __restrict__ gammaf,
                                                 const bf16* __restrict__ dist,
                                                 bf16* __restrict__ O) {
  int bh = blockIdx.x % (B_ * H_);        // idx%8 == bh%8 -> same-bh same XCD
  int q0 = (blockIdx.x / (B_ * H_)) * 128;
  int b = bh / H_, h = bh % H_;
  int tid = threadIdx.x, wave = tid >> 6, lane = tid & 63;
  int l5 = lane & 31, hh = lane >> 5, l7 = lane & 7;
  __shared__ __align__(16) bf16 Ks[128 * 64];   // [token][d], 16B slots XOR row&7
  __shared__ __align__(16) bf16 Vs[64 * 128];   // [d][token], 16B slots XOR row&7
  __shared__ float Ls[4 * 32];                  // per-wave 1/lsum slab

  // Q B-fragments: row = q (lane&31), k-elems d = st*16 + hh*8 + j
  bf16x8 aq[4];
  {
    const bf16* Qg = Q + ((size_t)bh * N_ + q0 + wave * 32 + l5) * DH_ + hh * 8;
#pragma unroll
    for (int st = 0; st < 4; st++) aq[st] = *(const bf16x8*)(Qg + st * 16);
  }

  floatx16 oacc[2] = {};
  float lsum = 0.f;
  const float LOG2E = 1.4426950408889634f;
  float gl = gammaf[b] * LOG2E;

  const bf16* Kg0 = Kp + (size_t)bh * N_ * DH_;
  const bf16* Vg0 = Vt + (size_t)bh * DH_ * N_;
  const bf16* Dg  = dist + (size_t)(q0 + wave * 32 + l5) * N_ + hh * 4;

  // staging: thread t owns 4 K-slots (id>>3 = row, id&7 = slot) and 4 V-slots
  // (id>>4 = row, id&15 = slot); LDS position swizzled, global linear.
  int kofs[4], vofs[4];
  const bf16* kg[4]; const bf16* vg[4];
#pragma unroll
  for (int i = 0; i < 4; i++) {
    int id = tid + i * 256;
    int kr = id >> 3, ksl = id & 7;
    kofs[i] = kr * 128 + ((ksl ^ (kr & 7)) * 16);
    kg[i] = Kg0 + (size_t)kr * DH_ + ksl * 8;
    int vr = id >> 4, vsl = id & 15;
    vofs[i] = vr * 256 + ((vsl ^ (vr & 7)) * 16);
    vg[i] = Vg0 + (size_t)vr * N_ + vsl * 8;
  }
  int krd = l5 * 128;     // + sub*4096 + ((st*2+hh)^l7)*16
  int vrd = l5 * 256;     // + t*8192  + ((sub*4+kk*2+hh)^l7)*16

  for (int t0 = 0; t0 < N_; t0 += 128) {
    // issue all global loads for this tile (latency overlaps barrier wait)
    bf16x8 kv[4], vv[4];
#pragma unroll
    for (int i = 0; i < 4; i++) kv[i] = *(const bf16x8*)(kg[i] + (size_t)t0 * DH_);
#pragma unroll
    for (int i = 0; i < 4; i++) vv[i] = *(const bf16x8*)(vg[i] + t0);
    bf16x4 ddr[16];       // dist in the C/D k-pattern: k = (r&3)+8*(r>>2)+4*hh
#pragma unroll
    for (int sub = 0; sub < 4; sub++)
#pragma unroll
      for (int jj = 0; jj < 4; jj++)
        ddr[sub * 4 + jj] = *(const bf16x4*)(Dg + t0 + sub * 32 + jj * 8);

    __syncthreads();      // all waves done reading Ks/Vs of previous tile
#pragma unroll
    for (int i = 0; i < 4; i++) *(bf16x8*)((char*)Ks + kofs[i]) = kv[i];
#pragma unroll
    for (int i = 0; i < 4; i++) *(bf16x8*)((char*)Vs + vofs[i]) = vv[i];
    __syncthreads();      // tile visible

#pragma unroll
    for (int sub = 0; sub < 4; sub++) {
      // S^T subtile: D[m=token][n=q], reduction over d (4 x K=16)
      floatx16 s = {};
      __builtin_amdgcn_s_setprio(1);
#pragma unroll
      for (int st = 0; st < 4; st++) {
        bf16x8 ak = *(const bf16x8*)((char*)Ks + sub * 4096 + krd +
                                     (((st * 2 + hh) ^ l7) * 16));
        s = __builtin_amdgcn_mfma_f32_32x32x16_bf16(ak, aq[st], s, 0, 0, 0);
      }
      __builtin_amdgcn_s_setprio(0);

      // softmax on 16 in-register values (Q pre-scaled: arg = s - gl*d)
      float p[16];
#pragma unroll
      for (int r = 0; r < 16; r++) {
        float df = (float)ddr[sub * 4 + (r >> 2)][r & 3];
        p[r] = __builtin_exp2f(__builtin_fmaf(-gl, df, s[r]));
        lsum += p[r];
      }
      // pack pairs -> bf16 words; permlane32_swap: a'=[a_lo|b_lo], b'=[a_hi|b_hi]
      unsigned pw[8];
#pragma unroll
      for (int i = 0; i < 8; i++) {
        unsigned o_;
        asm("v_cvt_pk_bf16_f32 %0, %1, %2"
            : "=v"(o_) : "v"(p[2 * i]), "v"(p[2 * i + 1]));
        pw[i] = o_;
      }
      asm("v_permlane32_swap_b32 %0, %1" : "+v"(pw[0]), "+v"(pw[2]));
      asm("v_permlane32_swap_b32 %0, %1" : "+v"(pw[1]), "+v"(pw[3]));
      asm("v_permlane32_swap_b32 %0, %1" : "+v"(pw[4]), "+v"(pw[6]));
      asm("v_permlane32_swap_b32 %0, %1" : "+v"(pw[5]), "+v"(pw[7]));
      bf16x8 pa0, pa1;    // A-frags: A[q=lane&31][k = kk*16 + hh*8 + j]
      { uint32x4 u0 = { pw[0], pw[1], pw[2], pw[3] }; pa0 = *(bf16x8*)&u0; }
      { uint32x4 u1 = { pw[4], pw[5], pw[6], pw[7] }; pa1 = *(bf16x8*)&u1; }

      __builtin_amdgcn_s_setprio(1);
#pragma unroll
      for (int t = 0; t < 2; t++) {
        bf16x8 bv0 = *(const bf16x8*)((char*)Vs + t * 8192 + vrd +
                                      (((sub * 4 + hh) ^ l7) * 16));
        oacc[t] = __builtin_amdgcn_mfma_f32_32x32x16_bf16(pa0, bv0, oacc[t], 0, 0, 0);
        bf16x8 bv1 = *(const bf16x8*)((char*)Vs + t * 8192 + vrd +
                                      (((sub * 4 + 2 + hh) ^ l7) * 16));
        oacc[t] = __builtin_amdgcn_mfma_f32_32x32x16_bf16(pa1, bv1, oacc[t], 0, 0, 0);
      }
      __builtin_amdgcn_s_setprio(0);
    }
  }

  // lsum(q) = lo-half + hi-half partial sums; broadcast 1/lsum via LDS slab
  lsum += __shfl_xor(lsum, 32, 64);
  float inv = 1.f / lsum;
  Ls[wave * 32 + l5] = inv;         // lanes l, l+32 write same value: benign
  __syncthreads();
  size_t obase = ((size_t)b * N_ + q0 + wave * 32) * D_ + h * DH_;
#pragma unroll
  for (int r = 0; r < 16; r++) {
    int qrow = (r & 3) + 8 * (r >> 2) + 4 * hh;
    float iv = Ls[wave * 32 + qrow];
#pragma unroll
    for (int t = 0; t < 2; t++)
      O[obase + (size_t)qrow * D_ + t * 32 + l5] = (bf16)(oacc[t][r] * iv);
  }
}

extern "C" void kernel_launch(void* const* d_in, const int* in_sizes, int n_in,
                              void* d_out, int out_size, void* d_ws, size_t ws_size,
                              hipStream_t stream) {
  const void* x     = d_in[0];
  const void* gamma = d_in[1];
  const void* dist  = d_in[2];
  const void* Wqkv  = d_in[3];
  const void* bqkv  = d_in[4];
  const void* Wproj = d_in[5];
  const void* bproj = d_in[6];

  char* ws = (char*)d_ws;
  size_t o = 0;
  int*   flag   = (int*)(ws + o);   o += 16;
  float* gammaf = (float*)(ws + o); o += 32;
  bf16*  xb     = (bf16*)(ws + o);  o += (size_t)M_ * D_ * 2;
  bf16*  distb  = (bf16*)(ws + o);  o += (size_t)N_ * N_ * 2;
  bf16*  bqkvb  = (bf16*)(ws + o);  o += (size_t)D3_ * 2;
  bf16*  bprojb = (bf16*)(ws + o);  o += (size_t)D_ * 2 + 8;
  bf16*  WqkvT  = (bf16*)(ws + o);  o += (size_t)D3_ * D_ * 2;
  bf16*  WprojT = (bf16*)(ws + o);  o += (size_t)D_ * D_ * 2;
  bf16*  Qp     = (bf16*)(ws + o);  o += (size_t)M_ * D_ * 2;
  bf16*  Kp     = (bf16*)(ws + o);  o += (size_t)M_ * D_ * 2;
  bf16*  Vtp    = (bf16*)(ws + o);  o += (size_t)M_ * D_ * 2;
  bf16*  Op     = (bf16*)(ws + o);  o += (size_t)M_ * D_ * 2;
  if (ws_size < o) return;

  detect_small_k<<<1, 256, 0, stream>>>((const unsigned int*)x, bqkv, bproj, gamma,
                                        flag, bqkvb, bprojb, gammaf);
  ingest2_k<<<XBLOCKS + DBLOCKS, 256, 0, stream>>>(x, xb, dist, distb, flag);
  int tilesA = (D3_ / 64) * (D_ / 64);          // 432
  int tilesB = (D_ / 64) * (D_ / 64);           // 144
  ingest_wt_k<<<tilesA + tilesB, 256, 0, stream>>>(Wqkv, WqkvT, Wproj, WprojT,
                                                   flag, tilesA, D3_ / 64);

  // QKV: grid 18 x 64 -> 1D 1152, BYL = 64/8 = 8
  gemm_bt<0, 4, 8><<<18 * 64, 256, 0, stream>>>(
      xb, WqkvT, bqkvb, Qp, Kp, Vtp, nullptr, flag, D_);
  attn_k<<<dim3(B_ * H_ * (N_ / 128)), 256, 0, stream>>>(
      Qp, Kp, Vtp, gammaf, distb, Op);
  // proj: grid 6 x 128 -> 1D 768, BYL = 128/8 = 16
  gemm_bt<1, 2, 16><<<6 * 128, 256, 0, stream>>>(
      Op, WprojT, bprojb, (bf16*)d_out, nullptr, nullptr, (float*)d_out, flag, D_);
}